// Round 8
// baseline (200.943 us; speedup 1.0000x reference)
//
#include <hip/hip_runtime.h>
#include <math.h>

#define L 2048
#define D 1024
#define H 16
#define KS 64
#define BBATCH 2

typedef float f32x4 __attribute__((ext_vector_type(4)));
typedef short s16x8 __attribute__((ext_vector_type(8)));

__device__ __forceinline__ ushort f2bf(float f) {
    union { float f; unsigned u; } v; v.f = f;
    unsigned lsb = (v.u >> 16) & 1u;
    v.u += 0x7fffu + lsb;               // round-to-nearest-even
    return (ushort)(v.u >> 16);
}

__device__ __forceinline__ unsigned fbits(float f) {
    union { float f; unsigned u; } v; v.f = f; return v.u;
}

__device__ __forceinline__ void gl_lds16(const ushort* g, ushort* l) {
    __builtin_amdgcn_global_load_lds(
        (const __attribute__((address_space(1))) unsigned int*)g,
        (__attribute__((address_space(3))) unsigned int*)l, 16, 0, 0);
}

// ---------------------------------------------------------------------------
// Fused prep: conv_x (blocks 0..4095) | conv_w x4 (4096..8191) |
// RoPE table (8192..8447): tab[dd2*2048+s] = (cos, sin) of s*10000^(-2*dd2/64)
// ---------------------------------------------------------------------------
__global__ __launch_bounds__(256)
void prep(const float* __restrict__ x,
          const float* __restrict__ W0, const float* __restrict__ W1,
          const float* __restrict__ W2, const float* __restrict__ W3,
          ushort* __restrict__ xb, ushort* __restrict__ Wt,
          float2* __restrict__ tab)
{
    __shared__ float T[32][33];
    const int bid = blockIdx.x;
    const int tid = threadIdx.x;
    if (bid < 4096) {
        const int i = bid * 1024 + tid * 4;
        const float4 v = *(const float4*)&x[i];
        ushort4 p = make_ushort4(f2bf(v.x), f2bf(v.y), f2bf(v.z), f2bf(v.w));
        *(ushort4*)&xb[i] = p;
    } else if (bid < 8192) {
        const int t = bid - 4096;
        const int z = t >> 10;
        const float* W = (z == 0) ? W0 : (z == 1) ? W1 : (z == 2) ? W2 : W3;
        ushort* out = Wt + (size_t)z * D * D;
        const int r0 = ((t >> 5) & 31) * 32, c0 = (t & 31) * 32;
        const int tr = tid >> 3, tc = (tid & 7) * 4;
        const float4 v = *(const float4*)&W[(size_t)(r0 + tr) * D + c0 + tc];
        T[tr][tc + 0] = v.x; T[tr][tc + 1] = v.y;
        T[tr][tc + 2] = v.z; T[tr][tc + 3] = v.w;
        __syncthreads();
        ushort4 p = make_ushort4(f2bf(T[tc + 0][tr]), f2bf(T[tc + 1][tr]),
                                 f2bf(T[tc + 2][tr]), f2bf(T[tc + 3][tr]));
        *(ushort4*)&out[(size_t)(c0 + tr) * D + r0 + tc] = p;
    } else {
        const int idx = (bid - 8192) * 256 + tid;    // 0..65535
        const int dd2 = idx >> 11, s = idx & 2047;
        const float inv = __expf(-(float)(2 * dd2) * (9.210340371976184f / 64.0f));
        float sn, cs;
        sincosf((float)s * inv, &sn, &cs);
        tab[idx] = make_float2(cs, sn);
    }
}

// ---------------------------------------------------------------------------
// Fused QKV GEMM, 128x128 tile, BK=32, 4 waves (2x2).
// A = stacked [Wq^T;Wk^T;Wv^T] (3072 x 1024), B = xb (4096 x 1024).
// Q/K epilogue: RoPE via table, DIRECT ushort4 stores (round-7 LDS-transpose
// epilogue regressed: occupancy drop outweighed store coalescing).
// V: per-wave LDS transpose -> Vt.
// ---------------------------------------------------------------------------
__global__ __launch_bounds__(256)
void qkv_gemm(const ushort* __restrict__ A, const ushort* __restrict__ B,
              const float2* __restrict__ tab,
              ushort* __restrict__ Qo, ushort* __restrict__ Ko,
              ushort* __restrict__ Vto)
{
    __shared__ __align__(16) ushort smem[18432];   // staging(8192) / V-T(18432)
    ushort* As = smem;            // [128][32]
    ushort* Bs = smem + 4096;     // [128][32]

    const int tid  = threadIdx.x;
    const int wv   = tid >> 6, lane = tid & 63;
    const int i16  = lane & 15, quad = lane >> 4;
    const int wr   = wv >> 1, wc = wv & 1;
    const int m0   = blockIdx.y * 128;
    const int n0   = blockIdx.x * 128;

    f32x4 acc[4][4];
    #pragma unroll
    for (int i = 0; i < 4; ++i)
        #pragma unroll
        for (int j = 0; j < 4; ++j) acc[i][j] = (f32x4){0.f, 0.f, 0.f, 0.f};

    for (int k0 = 0; k0 < D; k0 += 32) {
        __syncthreads();
        {
            int c = wv * 64 + lane;
            gl_lds16(A + (size_t)(m0 + (c >> 2)) * D + k0 + (c & 3) * 8,
                     As + (size_t)(wv * 64) * 8);
            c = 256 + wv * 64 + lane;
            gl_lds16(A + (size_t)(m0 + (c >> 2)) * D + k0 + (c & 3) * 8,
                     As + (size_t)(256 + wv * 64) * 8);
        }
        {
            int c = wv * 64 + lane;
            gl_lds16(B + (size_t)(n0 + (c >> 2)) * D + k0 + (c & 3) * 8,
                     Bs + (size_t)(wv * 64) * 8);
            c = 256 + wv * 64 + lane;
            gl_lds16(B + (size_t)(n0 + (c >> 2)) * D + k0 + (c & 3) * 8,
                     Bs + (size_t)(256 + wv * 64) * 8);
        }
        __syncthreads();
        s16x8 af[4], bf[4];
        #pragma unroll
        for (int mt = 0; mt < 4; ++mt)
            af[mt] = *(const s16x8*)&As[(wr * 64 + mt * 16 + i16) * 32 + quad * 8];
        #pragma unroll
        for (int nt = 0; nt < 4; ++nt)
            bf[nt] = *(const s16x8*)&Bs[(wc * 64 + nt * 16 + i16) * 32 + quad * 8];
        #pragma unroll
        for (int mt = 0; mt < 4; ++mt)
            #pragma unroll
            for (int nt = 0; nt < 4; ++nt)
                acc[mt][nt] = __builtin_amdgcn_mfma_f32_16x16x32_bf16(
                    af[mt], bf[nt], acc[mt][nt], 0, 0, 0);
    }

    if (m0 < 2048) {
        // ---- Q or K: RoPE epilogue via table, direct stores ----
        const bool isQ = (m0 < 1024);
        ushort* out = isQ ? Qo : Ko;
        const int mb = isQ ? m0 : (m0 - 1024);
        #pragma unroll
        for (int mt = 0; mt < 4; ++mt)
            #pragma unroll
            for (int nt = 0; nt < 4; ++nt) {
                const int token = n0 + wc * 64 + nt * 16 + i16;
                const int b = token >> 11, s = token & 2047;
                const int dim = mb + wr * 64 + mt * 16 + quad * 4;
                const int hh = dim >> 6, dd = dim & 63;
                ushort4 p;
                #pragma unroll
                for (int pr = 0; pr < 2; ++pr) {
                    float e = acc[mt][nt][2 * pr];
                    float o = acc[mt][nt][2 * pr + 1];
                    if (isQ) { e *= 0.03125f; o *= 0.03125f; }
                    const float2 cssn = tab[(size_t)((dd >> 1) + pr) * 2048 + s];
                    const float ne = e * cssn.x - o * cssn.y;
                    const float no = o * cssn.x + e * cssn.y;
                    if (pr == 0) { p.x = f2bf(ne); p.y = f2bf(no); }
                    else         { p.z = f2bf(ne); p.w = f2bf(no); }
                }
                *(ushort4*)&out[((size_t)(b * H + hh) * L + s) * KS + dd] = p;
            }
    } else {
        // ---- V: per-wave LDS transpose -> coalesced Vt stores ----
        __syncthreads();                       // staging buffers done
        ushort* T = smem + wv * 4608;          // [64][72] per wave
        const int vbase = (m0 - 2048) + wr * 64;
        const int tbase = n0 + wc * 64;
        #pragma unroll
        for (int mt = 0; mt < 4; ++mt)
            #pragma unroll
            for (int nt = 0; nt < 4; ++nt) {
                const int tl = nt * 16 + i16;
                #pragma unroll
                for (int r = 0; r < 4; ++r)
                    T[(mt * 16 + quad * 4 + r) * 72 + tl] = f2bf(acc[mt][nt][r]);
            }
        __builtin_amdgcn_s_waitcnt(0);         // wave-local LDS drain
        const int tl0 = (lane & 7) * 8;
        #pragma unroll
        for (int c = 0; c < 8; ++c) {
            const int vl = c * 8 + (lane >> 3);
            const s16x8 val = *(const s16x8*)&T[vl * 72 + tl0];
            const int vdim = vbase + vl;
            const int hh = vdim >> 6, dd = vdim & 63;
            const int token0 = tbase + tl0;
            const int b = token0 >> 11, s0 = token0 & 2047;
            *(s16x8*)&Vto[((size_t)(b * H + hh) * KS + dd) * L + s0] = val;
        }
    }
}

// ---------------------------------------------------------------------------
// O-projection GEMM: out = Y @ Wo. Tile 128 tokens x 64 dims -> 512 blocks.
// ---------------------------------------------------------------------------
__global__ __launch_bounds__(256)
void oproj_gemm(const ushort* __restrict__ A, const ushort* __restrict__ B,
                float* __restrict__ out)
{
    __shared__ __align__(16) ushort As[128 * 32];
    __shared__ __align__(16) ushort Bs[64 * 32];
    const int tid  = threadIdx.x;
    const int wv   = tid >> 6, lane = tid & 63;
    const int i16  = lane & 15, quad = lane >> 4;
    const int wr   = wv >> 1, wc = wv & 1;
    const int m0   = blockIdx.y * 128;   // tokens
    const int n0   = blockIdx.x * 64;    // out-dims

    f32x4 acc[4][2];
    #pragma unroll
    for (int i = 0; i < 4; ++i)
        #pragma unroll
        for (int j = 0; j < 2; ++j) acc[i][j] = (f32x4){0.f, 0.f, 0.f, 0.f};

    for (int k0 = 0; k0 < D; k0 += 32) {
        __syncthreads();
        {
            int c = wv * 64 + lane;
            gl_lds16(A + (size_t)(m0 + (c >> 2)) * D + k0 + (c & 3) * 8,
                     As + (size_t)(wv * 64) * 8);
            c = 256 + wv * 64 + lane;
            gl_lds16(A + (size_t)(m0 + (c >> 2)) * D + k0 + (c & 3) * 8,
                     As + (size_t)(256 + wv * 64) * 8);
        }
        {
            int c = wv * 64 + lane;   // 256 chunks: full Bs coverage
            gl_lds16(B + (size_t)(n0 + (c >> 2)) * D + k0 + (c & 3) * 8,
                     Bs + (size_t)(wv * 64) * 8);
        }
        __syncthreads();
        s16x8 af[4], bf[2];
        #pragma unroll
        for (int mt = 0; mt < 4; ++mt)
            af[mt] = *(const s16x8*)&As[(wr * 64 + mt * 16 + i16) * 32 + quad * 8];
        #pragma unroll
        for (int nt = 0; nt < 2; ++nt)
            bf[nt] = *(const s16x8*)&Bs[(wc * 32 + nt * 16 + i16) * 32 + quad * 8];
        #pragma unroll
        for (int mt = 0; mt < 4; ++mt)
            #pragma unroll
            for (int nt = 0; nt < 2; ++nt)
                acc[mt][nt] = __builtin_amdgcn_mfma_f32_16x16x32_bf16(
                    af[mt], bf[nt], acc[mt][nt], 0, 0, 0);
    }

    #pragma unroll
    for (int mt = 0; mt < 4; ++mt)
        #pragma unroll
        for (int nt = 0; nt < 2; ++nt) {
            const int od = n0 + wc * 32 + nt * 16 + i16;
            const int tk = m0 + wr * 64 + mt * 16 + quad * 4;
            #pragma unroll
            for (int r = 0; r < 4; ++r)
                out[(size_t)(tk + r) * D + od] = acc[mt][nt][r];
        }
}

// ---------------------------------------------------------------------------
// MFMA flash attention: fixed-max softmax, paired q-tiles (qa, 31-qa),
// DOUBLE-BUFFERED K/V staging -> ONE barrier per key-tile (was two).
// 512 thr = 8 waves; waves 0-3 -> qa, 4-7 -> qb. Uniform per-block work
// (qa+qb+2 = 34 phases) so the 55KB-LDS 2-blocks/CU cap costs nothing.
// ---------------------------------------------------------------------------
__global__ __launch_bounds__(512)
void attn_mfma(const ushort* __restrict__ Q, const ushort* __restrict__ K,
               const ushort* __restrict__ Vt, ushort* __restrict__ Yb)
{
    const int bh   = blockIdx.y;
    const int qa   = blockIdx.x;             // 0..15
    const int qb   = 31 - qa;
    const int tid  = threadIdx.x;
    const int wave = tid >> 6, lane = tid & 63;
    const int half = wave >> 2, wv4 = wave & 3;
    const int i16  = lane & 15, quad = lane >> 4;
    const int qt   = half ? qb : qa;
    const int r0   = qt * 64 + wv4 * 16;
    const int row  = r0 + i16;

    __shared__ ushort Ks[2][64 * 72];
    __shared__ ushort Vs[2][64 * 72];
    __shared__ ushort Ps[8][16 * 72];

    const ushort* Qb = Q  + (size_t)bh * L * KS;
    const ushort* Kb = K  + (size_t)bh * L * KS;
    const ushort* Vb = Vt + (size_t)bh * KS * L;

    const s16x8 qf0 = *(const s16x8*)(Qb + (size_t)row * KS + quad * 8);
    const s16x8 qf1 = *(const s16x8*)(Qb + (size_t)row * KS + 32 + quad * 8);

    // prologue: stage tile 0 into buffer 0 (1024 chunks over 512 threads)
    const int sr = tid >> 3, sseg = (tid & 7) * 8;
    s16x8 kpre = *(const s16x8*)(Kb + (size_t)sr * KS + sseg);
    s16x8 vpre = *(const s16x8*)(Vb + (size_t)sr * L + sseg);
    *(s16x8*)&Ks[0][sr * 72 + sseg] = kpre;
    *(s16x8*)&Vs[0][sr * 72 + sseg] = vpre;
    __syncthreads();

    f32x4 O0 = {0.f,0.f,0.f,0.f}, O1 = O0, O2 = O0, O3 = O0;
    float psum = 0.0f;

    for (int jt = 0; jt <= qb; ++jt) {
        const int cur = jt & 1;
        const bool has_next = (jt < qb);

        // ---- issue next-tile global loads (land during compute) -----------
        if (has_next) {
            const int j0n = (jt + 1) * 64;
            kpre = *(const s16x8*)(Kb + (size_t)(j0n + sr) * KS + sseg);
            vpre = *(const s16x8*)(Vb + (size_t)sr * L + j0n + sseg);
        }

        if (jt <= qt) {
            const int j0 = jt * 64;
            const ushort* Ksb = &Ks[cur][0];
            const ushort* Vsb = &Vs[cur][0];
            // ---- St = K Q^T ----
            f32x4 st[4];
            #pragma unroll
            for (int nt = 0; nt < 4; ++nt) {
                const s16x8 kf0 = *(const s16x8*)&Ksb[(nt * 16 + i16) * 72 + quad * 8];
                const s16x8 kf1 = *(const s16x8*)&Ksb[(nt * 16 + i16) * 72 + 32 + quad * 8];
                f32x4 c = {0.f,0.f,0.f,0.f};
                c = __builtin_amdgcn_mfma_f32_16x16x32_bf16(kf0, qf0, c, 0, 0, 0);
                c = __builtin_amdgcn_mfma_f32_16x16x32_bf16(kf1, qf1, c, 0, 0, 0);
                st[nt] = c;
            }
            // ---- causal mask on boundary tile ----
            if (jt == qt) {
                #pragma unroll
                for (int nt = 0; nt < 4; ++nt)
                    #pragma unroll
                    for (int rg = 0; rg < 4; ++rg) {
                        const int j = j0 + nt * 16 + quad * 4 + rg;
                        if (j > row) st[nt][rg] = -1e30f;
                    }
            }
            // ---- fixed-max softmax: p = exp(logit) ----
            float pv[4][4];
            #pragma unroll
            for (int nt = 0; nt < 4; ++nt)
                #pragma unroll
                for (int rg = 0; rg < 4; ++rg) {
                    pv[nt][rg] = __expf(st[nt][rg]);
                    psum += pv[nt][rg];
                }
            // ---- pack P (truncation) -> per-wave LDS -> A-layout frags ----
            ushort* P2 = &Ps[wave][0];
            #pragma unroll
            for (int nt = 0; nt < 4; ++nt) {
                uint2 pk;
                pk.x = __builtin_amdgcn_perm(fbits(pv[nt][1]), fbits(pv[nt][0]), 0x07060302u);
                pk.y = __builtin_amdgcn_perm(fbits(pv[nt][3]), fbits(pv[nt][2]), 0x07060302u);
                *(uint2*)(P2 + i16 * 72 + nt * 16 + quad * 4) = pk;
            }
            const s16x8 pf0 = *(const s16x8*)(P2 + i16 * 72 + quad * 8);
            const s16x8 pf1 = *(const s16x8*)(P2 + i16 * 72 + 32 + quad * 8);
            // ---- O^T += V^T P^T ----
            s16x8 v0, v1;
            v0 = *(const s16x8*)&Vsb[(0 * 16 + i16) * 72 + quad * 8];
            v1 = *(const s16x8*)&Vsb[(0 * 16 + i16) * 72 + 32 + quad * 8];
            O0 = __builtin_amdgcn_mfma_f32_16x16x32_bf16(v0, pf0, O0, 0, 0, 0);
            O0 = __builtin_amdgcn_mfma_f32_16x16x32_bf16(v1, pf1, O0, 0, 0, 0);
            v0 = *(const s16x8*)&Vsb[(1 * 16 + i16) * 72 + quad * 8];
            v1 = *(const s16x8*)&Vsb[(1 * 16 + i16) * 72 + 32 + quad * 8];
            O1 = __builtin_amdgcn_mfma_f32_16x16x32_bf16(v0, pf0, O1, 0, 0, 0);
            O1 = __builtin_amdgcn_mfma_f32_16x16x32_bf16(v1, pf1, O1, 0, 0, 0);
            v0 = *(const s16x8*)&Vsb[(2 * 16 + i16) * 72 + quad * 8];
            v1 = *(const s16x8*)&Vsb[(2 * 16 + i16) * 72 + 32 + quad * 8];
            O2 = __builtin_amdgcn_mfma_f32_16x16x32_bf16(v0, pf0, O2, 0, 0, 0);
            O2 = __builtin_amdgcn_mfma_f32_16x16x32_bf16(v1, pf1, O2, 0, 0, 0);
            v0 = *(const s16x8*)&Vsb[(3 * 16 + i16) * 72 + quad * 8];
            v1 = *(const s16x8*)&Vsb[(3 * 16 + i16) * 72 + 32 + quad * 8];
            O3 = __builtin_amdgcn_mfma_f32_16x16x32_bf16(v0, pf0, O3, 0, 0, 0);
            O3 = __builtin_amdgcn_mfma_f32_16x16x32_bf16(v1, pf1, O3, 0, 0, 0);
        }

        // ---- stage next tile into the OTHER buffer; one barrier -----------
        if (has_next) {
            *(s16x8*)&Ks[cur ^ 1][sr * 72 + sseg] = kpre;
            *(s16x8*)&Vs[cur ^ 1][sr * 72 + sseg] = vpre;
            __syncthreads();
        }
    }

    // ---- epilogue ----
    psum += __shfl_xor(psum, 16);
    psum += __shfl_xor(psum, 32);
    const float inv_l = __builtin_amdgcn_rcpf(psum);
    const int b = bh >> 4, hh = bh & 15;
    ushort* Yp = Yb + ((size_t)(b * L + row)) * D + hh * KS + quad * 4;
    f32x4 r;
    r = O0 * inv_l; *(ushort4*)(Yp +  0) = make_ushort4(f2bf(r[0]),f2bf(r[1]),f2bf(r[2]),f2bf(r[3]));
    r = O1 * inv_l; *(ushort4*)(Yp + 16) = make_ushort4(f2bf(r[0]),f2bf(r[1]),f2bf(r[2]),f2bf(r[3]));
    r = O2 * inv_l; *(ushort4*)(Yp + 32) = make_ushort4(f2bf(r[0]),f2bf(r[1]),f2bf(r[2]),f2bf(r[3]));
    r = O3 * inv_l; *(ushort4*)(Yp + 48) = make_ushort4(f2bf(r[0]),f2bf(r[1]),f2bf(r[2]),f2bf(r[3]));
}

// ---------------------------------------------------------------------------
extern "C" void kernel_launch(void* const* d_in, const int* in_sizes, int n_in,
                              void* d_out, int out_size, void* d_ws, size_t ws_size,
                              hipStream_t stream)
{
    const float* x  = (const float*)d_in[0];
    // d_in[1] = mask (unused; causal handled analytically)
    const float* Wq = (const float*)d_in[2];
    const float* Wk = (const float*)d_in[3];
    const float* Wv = (const float*)d_in[4];
    const float* Wo = (const float*)d_in[5];

    const size_t NTOK = (size_t)BBATCH * L;         // 4096
    const size_t SZ   = NTOK * D;                   // 4 M elems
    ushort* xb  = (ushort*)d_ws;                    // [4096][1024]
    ushort* Wt  = xb + SZ;                          // [Wq^T;Wk^T;Wv^T;Wo^T]
    ushort* Qb  = Wt + 4 * (size_t)D * D;           // [bh][l][64]
    ushort* Kb  = Qb + SZ;
    ushort* Vtb = Kb + SZ;                          // [bh][64][l]
    ushort* Yb  = Vtb + SZ;                         // [4096][1024]
    float2* tab = (float2*)Yb;                      // aliases Yb: consumed by
                                                    // qkv before attn writes Yb

    prep<<<dim3(8448), dim3(256), 0, stream>>>(x, Wq, Wk, Wv, Wo, xb, Wt, tab);

    qkv_gemm<<<dim3(32, 24), dim3(256), 0, stream>>>(Wt, xb, tab, Qb, Kb, Vtb);

    attn_mfma<<<dim3(16, 32), dim3(512), 0, stream>>>(Qb, Kb, Vtb, Yb);

    oproj_gemm<<<dim3(16, 32), dim3(256), 0, stream>>>(Yb, Wt + 3 * (size_t)D * D,
                                                       (float*)d_out);
}

// Round 9
// 194.175 us; speedup vs baseline: 1.0349x; 1.0349x over previous
//
#include <hip/hip_runtime.h>
#include <math.h>

#define L 2048
#define D 1024
#define H 16
#define KS 64
#define BBATCH 2

typedef float f32x4 __attribute__((ext_vector_type(4)));
typedef short s16x8 __attribute__((ext_vector_type(8)));

__device__ __forceinline__ ushort f2bf(float f) {
    union { float f; unsigned u; } v; v.f = f;
    unsigned lsb = (v.u >> 16) & 1u;
    v.u += 0x7fffu + lsb;               // round-to-nearest-even
    return (ushort)(v.u >> 16);
}

__device__ __forceinline__ unsigned fbits(float f) {
    union { float f; unsigned u; } v; v.f = f; return v.u;
}

__device__ __forceinline__ void gl_lds16(const ushort* g, ushort* l) {
    __builtin_amdgcn_global_load_lds(
        (const __attribute__((address_space(1))) unsigned int*)g,
        (__attribute__((address_space(3))) unsigned int*)l, 16, 0, 0);
}

// ---------------------------------------------------------------------------
// Fused prep: conv_x (blocks 0..4095) | conv_w x4 (4096..8191) |
// RoPE table (8192..8447): tab[dd2*2048+s] = (cos, sin) of s*10000^(-2*dd2/64)
// ---------------------------------------------------------------------------
__global__ __launch_bounds__(256)
void prep(const float* __restrict__ x,
          const float* __restrict__ W0, const float* __restrict__ W1,
          const float* __restrict__ W2, const float* __restrict__ W3,
          ushort* __restrict__ xb, ushort* __restrict__ Wt,
          float2* __restrict__ tab)
{
    __shared__ float T[32][33];
    const int bid = blockIdx.x;
    const int tid = threadIdx.x;
    if (bid < 4096) {
        const int i = bid * 1024 + tid * 4;
        const float4 v = *(const float4*)&x[i];
        ushort4 p = make_ushort4(f2bf(v.x), f2bf(v.y), f2bf(v.z), f2bf(v.w));
        *(ushort4*)&xb[i] = p;
    } else if (bid < 8192) {
        const int t = bid - 4096;
        const int z = t >> 10;
        const float* W = (z == 0) ? W0 : (z == 1) ? W1 : (z == 2) ? W2 : W3;
        ushort* out = Wt + (size_t)z * D * D;
        const int r0 = ((t >> 5) & 31) * 32, c0 = (t & 31) * 32;
        const int tr = tid >> 3, tc = (tid & 7) * 4;
        const float4 v = *(const float4*)&W[(size_t)(r0 + tr) * D + c0 + tc];
        T[tr][tc + 0] = v.x; T[tr][tc + 1] = v.y;
        T[tr][tc + 2] = v.z; T[tr][tc + 3] = v.w;
        __syncthreads();
        ushort4 p = make_ushort4(f2bf(T[tc + 0][tr]), f2bf(T[tc + 1][tr]),
                                 f2bf(T[tc + 2][tr]), f2bf(T[tc + 3][tr]));
        *(ushort4*)&out[(size_t)(c0 + tr) * D + r0 + tc] = p;
    } else {
        const int idx = (bid - 8192) * 256 + tid;    // 0..65535
        const int dd2 = idx >> 11, s = idx & 2047;
        const float inv = __expf(-(float)(2 * dd2) * (9.210340371976184f / 64.0f));
        float sn, cs;
        sincosf((float)s * inv, &sn, &cs);
        tab[idx] = make_float2(cs, sn);
    }
}

// ---------------------------------------------------------------------------
// Fused QKV GEMM, 128x128 tile, BK=32, 4 waves (2x2), DOUBLE-BUFFERED LDS
// staging: issue next-tile global_load_lds into buf^1, compute buf, one
// barrier (vmcnt drain overlaps compute). A = [Wq^T;Wk^T;Wv^T], B = xb.
// Q/K epilogue: RoPE via table, direct stores. V: per-wave LDS transpose
// (reuses the 32KB staging area after the final barrier).
// ---------------------------------------------------------------------------
__global__ __launch_bounds__(256)
void qkv_gemm(const ushort* __restrict__ A, const ushort* __restrict__ B,
              const float2* __restrict__ tab,
              ushort* __restrict__ Qo, ushort* __restrict__ Ko,
              ushort* __restrict__ Vto)
{
    __shared__ __align__(16) ushort smem[18432];   // dbuf staging 16384 / V-T 18432
    const int tid  = threadIdx.x;
    const int wv   = tid >> 6, lane = tid & 63;
    const int i16  = lane & 15, quad = lane >> 4;
    const int wr   = wv >> 1, wc = wv & 1;
    const int m0   = blockIdx.y * 128;
    const int n0   = blockIdx.x * 128;

    // per-thread staging chunk ids (two for A, two for B)
    const int cA0 = wv * 64 + lane, cA1 = 256 + wv * 64 + lane;

    f32x4 acc[4][4];
    #pragma unroll
    for (int i = 0; i < 4; ++i)
        #pragma unroll
        for (int j = 0; j < 4; ++j) acc[i][j] = (f32x4){0.f, 0.f, 0.f, 0.f};

    // prologue: stage k0=0 into buffer 0
    {
        ushort* As = smem;
        ushort* Bs = smem + 4096;
        gl_lds16(A + (size_t)(m0 + (cA0 >> 2)) * D + (cA0 & 3) * 8, As + (size_t)(wv * 64) * 8);
        gl_lds16(A + (size_t)(m0 + (cA1 >> 2)) * D + (cA1 & 3) * 8, As + (size_t)(256 + wv * 64) * 8);
        gl_lds16(B + (size_t)(n0 + (cA0 >> 2)) * D + (cA0 & 3) * 8, Bs + (size_t)(wv * 64) * 8);
        gl_lds16(B + (size_t)(n0 + (cA1 >> 2)) * D + (cA1 & 3) * 8, Bs + (size_t)(256 + wv * 64) * 8);
    }
    __syncthreads();

    for (int it = 0; it < 32; ++it) {
        const int cur = it & 1;
        // ---- issue next-tile loads into the other buffer ----
        if (it + 1 < 32) {
            const int kn = (it + 1) * 32;
            ushort* As = smem + (cur ^ 1) * 8192;
            ushort* Bs = As + 4096;
            gl_lds16(A + (size_t)(m0 + (cA0 >> 2)) * D + kn + (cA0 & 3) * 8, As + (size_t)(wv * 64) * 8);
            gl_lds16(A + (size_t)(m0 + (cA1 >> 2)) * D + kn + (cA1 & 3) * 8, As + (size_t)(256 + wv * 64) * 8);
            gl_lds16(B + (size_t)(n0 + (cA0 >> 2)) * D + kn + (cA0 & 3) * 8, Bs + (size_t)(wv * 64) * 8);
            gl_lds16(B + (size_t)(n0 + (cA1 >> 2)) * D + kn + (cA1 & 3) * 8, Bs + (size_t)(256 + wv * 64) * 8);
        }
        // ---- compute from current buffer ----
        const ushort* As = smem + cur * 8192;
        const ushort* Bs = As + 4096;
        s16x8 af[4], bf[4];
        #pragma unroll
        for (int mt = 0; mt < 4; ++mt)
            af[mt] = *(const s16x8*)&As[(wr * 64 + mt * 16 + i16) * 32 + quad * 8];
        #pragma unroll
        for (int nt = 0; nt < 4; ++nt)
            bf[nt] = *(const s16x8*)&Bs[(wc * 64 + nt * 16 + i16) * 32 + quad * 8];
        #pragma unroll
        for (int mt = 0; mt < 4; ++mt)
            #pragma unroll
            for (int nt = 0; nt < 4; ++nt)
                acc[mt][nt] = __builtin_amdgcn_mfma_f32_16x16x32_bf16(
                    af[mt], bf[nt], acc[mt][nt], 0, 0, 0);
        // one barrier: drains next-tile loads (overlapped with the MFMA above)
        __syncthreads();
    }

    if (m0 < 2048) {
        // ---- Q or K: RoPE epilogue via table, direct stores ----
        const bool isQ = (m0 < 1024);
        ushort* out = isQ ? Qo : Ko;
        const int mb = isQ ? m0 : (m0 - 1024);
        #pragma unroll
        for (int mt = 0; mt < 4; ++mt)
            #pragma unroll
            for (int nt = 0; nt < 4; ++nt) {
                const int token = n0 + wc * 64 + nt * 16 + i16;
                const int b = token >> 11, s = token & 2047;
                const int dim = mb + wr * 64 + mt * 16 + quad * 4;
                const int hh = dim >> 6, dd = dim & 63;
                ushort4 p;
                #pragma unroll
                for (int pr = 0; pr < 2; ++pr) {
                    float e = acc[mt][nt][2 * pr];
                    float o = acc[mt][nt][2 * pr + 1];
                    if (isQ) { e *= 0.03125f; o *= 0.03125f; }
                    const float2 cssn = tab[(size_t)((dd >> 1) + pr) * 2048 + s];
                    const float ne = e * cssn.x - o * cssn.y;
                    const float no = o * cssn.x + e * cssn.y;
                    if (pr == 0) { p.x = f2bf(ne); p.y = f2bf(no); }
                    else         { p.z = f2bf(ne); p.w = f2bf(no); }
                }
                *(ushort4*)&out[((size_t)(b * H + hh) * L + s) * KS + dd] = p;
            }
    } else {
        // ---- V: per-wave LDS transpose -> coalesced Vt stores ----
        ushort* T = smem + wv * 4608;          // [64][72] per wave
        const int vbase = (m0 - 2048) + wr * 64;
        const int tbase = n0 + wc * 64;
        #pragma unroll
        for (int mt = 0; mt < 4; ++mt)
            #pragma unroll
            for (int nt = 0; nt < 4; ++nt) {
                const int tl = nt * 16 + i16;
                #pragma unroll
                for (int r = 0; r < 4; ++r)
                    T[(mt * 16 + quad * 4 + r) * 72 + tl] = f2bf(acc[mt][nt][r]);
            }
        __builtin_amdgcn_s_waitcnt(0);         // wave-local LDS drain
        const int tl0 = (lane & 7) * 8;
        #pragma unroll
        for (int c = 0; c < 8; ++c) {
            const int vl = c * 8 + (lane >> 3);
            const s16x8 val = *(const s16x8*)&T[vl * 72 + tl0];
            const int vdim = vbase + vl;
            const int hh = vdim >> 6, dd = vdim & 63;
            const int token0 = tbase + tl0;
            const int b = token0 >> 11, s0 = token0 & 2047;
            *(s16x8*)&Vto[((size_t)(b * H + hh) * KS + dd) * L + s0] = val;
        }
    }
}

// ---------------------------------------------------------------------------
// O-projection GEMM, double-buffered staging. Tile 128 tok x 64 dims.
// ---------------------------------------------------------------------------
__global__ __launch_bounds__(256)
void oproj_gemm(const ushort* __restrict__ A, const ushort* __restrict__ B,
                float* __restrict__ out)
{
    __shared__ __align__(16) ushort smem[12288];  // 2 x (As 4096 + Bs 2048)
    const int tid  = threadIdx.x;
    const int wv   = tid >> 6, lane = tid & 63;
    const int i16  = lane & 15, quad = lane >> 4;
    const int wr   = wv >> 1, wc = wv & 1;
    const int m0   = blockIdx.y * 128;   // tokens
    const int n0   = blockIdx.x * 64;    // out-dims

    const int cA0 = wv * 64 + lane, cA1 = 256 + wv * 64 + lane;

    f32x4 acc[4][2];
    #pragma unroll
    for (int i = 0; i < 4; ++i)
        #pragma unroll
        for (int j = 0; j < 2; ++j) acc[i][j] = (f32x4){0.f, 0.f, 0.f, 0.f};

    {
        ushort* As = smem;
        ushort* Bs = smem + 4096;
        gl_lds16(A + (size_t)(m0 + (cA0 >> 2)) * D + (cA0 & 3) * 8, As + (size_t)(wv * 64) * 8);
        gl_lds16(A + (size_t)(m0 + (cA1 >> 2)) * D + (cA1 & 3) * 8, As + (size_t)(256 + wv * 64) * 8);
        gl_lds16(B + (size_t)(n0 + (cA0 >> 2)) * D + (cA0 & 3) * 8, Bs + (size_t)(wv * 64) * 8);
    }
    __syncthreads();

    for (int it = 0; it < 32; ++it) {
        const int cur = it & 1;
        if (it + 1 < 32) {
            const int kn = (it + 1) * 32;
            ushort* As = smem + (cur ^ 1) * 6144;
            ushort* Bs = As + 4096;
            gl_lds16(A + (size_t)(m0 + (cA0 >> 2)) * D + kn + (cA0 & 3) * 8, As + (size_t)(wv * 64) * 8);
            gl_lds16(A + (size_t)(m0 + (cA1 >> 2)) * D + kn + (cA1 & 3) * 8, As + (size_t)(256 + wv * 64) * 8);
            gl_lds16(B + (size_t)(n0 + (cA0 >> 2)) * D + kn + (cA0 & 3) * 8, Bs + (size_t)(wv * 64) * 8);
        }
        const ushort* As = smem + cur * 6144;
        const ushort* Bs = As + 4096;
        s16x8 af[4], bf[2];
        #pragma unroll
        for (int mt = 0; mt < 4; ++mt)
            af[mt] = *(const s16x8*)&As[(wr * 64 + mt * 16 + i16) * 32 + quad * 8];
        #pragma unroll
        for (int nt = 0; nt < 2; ++nt)
            bf[nt] = *(const s16x8*)&Bs[(wc * 32 + nt * 16 + i16) * 32 + quad * 8];
        #pragma unroll
        for (int mt = 0; mt < 4; ++mt)
            #pragma unroll
            for (int nt = 0; nt < 2; ++nt)
                acc[mt][nt] = __builtin_amdgcn_mfma_f32_16x16x32_bf16(
                    af[mt], bf[nt], acc[mt][nt], 0, 0, 0);
        __syncthreads();
    }

    #pragma unroll
    for (int mt = 0; mt < 4; ++mt)
        #pragma unroll
        for (int nt = 0; nt < 2; ++nt) {
            const int od = n0 + wc * 32 + nt * 16 + i16;
            const int tk = m0 + wr * 64 + mt * 16 + quad * 4;
            #pragma unroll
            for (int r = 0; r < 4; ++r)
                out[(size_t)(tk + r) * D + od] = acc[mt][nt][r];
        }
}

// ---------------------------------------------------------------------------
// MFMA flash attention: fixed-max softmax, paired q-tiles (qa, 31-qa),
// double-buffered K/V staging, one barrier per key-tile.
// ---------------------------------------------------------------------------
__global__ __launch_bounds__(512)
void attn_mfma(const ushort* __restrict__ Q, const ushort* __restrict__ K,
               const ushort* __restrict__ Vt, ushort* __restrict__ Yb)
{
    const int bh   = blockIdx.y;
    const int qa   = blockIdx.x;             // 0..15
    const int qb   = 31 - qa;
    const int tid  = threadIdx.x;
    const int wave = tid >> 6, lane = tid & 63;
    const int half = wave >> 2, wv4 = wave & 3;
    const int i16  = lane & 15, quad = lane >> 4;
    const int qt   = half ? qb : qa;
    const int r0   = qt * 64 + wv4 * 16;
    const int row  = r0 + i16;

    __shared__ ushort Ks[2][64 * 72];
    __shared__ ushort Vs[2][64 * 72];
    __shared__ ushort Ps[8][16 * 72];

    const ushort* Qb = Q  + (size_t)bh * L * KS;
    const ushort* Kb = K  + (size_t)bh * L * KS;
    const ushort* Vb = Vt + (size_t)bh * KS * L;

    const s16x8 qf0 = *(const s16x8*)(Qb + (size_t)row * KS + quad * 8);
    const s16x8 qf1 = *(const s16x8*)(Qb + (size_t)row * KS + 32 + quad * 8);

    const int sr = tid >> 3, sseg = (tid & 7) * 8;
    s16x8 kpre = *(const s16x8*)(Kb + (size_t)sr * KS + sseg);
    s16x8 vpre = *(const s16x8*)(Vb + (size_t)sr * L + sseg);
    *(s16x8*)&Ks[0][sr * 72 + sseg] = kpre;
    *(s16x8*)&Vs[0][sr * 72 + sseg] = vpre;
    __syncthreads();

    f32x4 O0 = {0.f,0.f,0.f,0.f}, O1 = O0, O2 = O0, O3 = O0;
    float psum = 0.0f;

    for (int jt = 0; jt <= qb; ++jt) {
        const int cur = jt & 1;
        const bool has_next = (jt < qb);

        if (has_next) {
            const int j0n = (jt + 1) * 64;
            kpre = *(const s16x8*)(Kb + (size_t)(j0n + sr) * KS + sseg);
            vpre = *(const s16x8*)(Vb + (size_t)sr * L + j0n + sseg);
        }

        if (jt <= qt) {
            const int j0 = jt * 64;
            const ushort* Ksb = &Ks[cur][0];
            const ushort* Vsb = &Vs[cur][0];
            f32x4 st[4];
            #pragma unroll
            for (int nt = 0; nt < 4; ++nt) {
                const s16x8 kf0 = *(const s16x8*)&Ksb[(nt * 16 + i16) * 72 + quad * 8];
                const s16x8 kf1 = *(const s16x8*)&Ksb[(nt * 16 + i16) * 72 + 32 + quad * 8];
                f32x4 c = {0.f,0.f,0.f,0.f};
                c = __builtin_amdgcn_mfma_f32_16x16x32_bf16(kf0, qf0, c, 0, 0, 0);
                c = __builtin_amdgcn_mfma_f32_16x16x32_bf16(kf1, qf1, c, 0, 0, 0);
                st[nt] = c;
            }
            if (jt == qt) {
                #pragma unroll
                for (int nt = 0; nt < 4; ++nt)
                    #pragma unroll
                    for (int rg = 0; rg < 4; ++rg) {
                        const int j = j0 + nt * 16 + quad * 4 + rg;
                        if (j > row) st[nt][rg] = -1e30f;
                    }
            }
            float pv[4][4];
            #pragma unroll
            for (int nt = 0; nt < 4; ++nt)
                #pragma unroll
                for (int rg = 0; rg < 4; ++rg) {
                    pv[nt][rg] = __expf(st[nt][rg]);
                    psum += pv[nt][rg];
                }
            ushort* P2 = &Ps[wave][0];
            #pragma unroll
            for (int nt = 0; nt < 4; ++nt) {
                uint2 pk;
                pk.x = __builtin_amdgcn_perm(fbits(pv[nt][1]), fbits(pv[nt][0]), 0x07060302u);
                pk.y = __builtin_amdgcn_perm(fbits(pv[nt][3]), fbits(pv[nt][2]), 0x07060302u);
                *(uint2*)(P2 + i16 * 72 + nt * 16 + quad * 4) = pk;
            }
            const s16x8 pf0 = *(const s16x8*)(P2 + i16 * 72 + quad * 8);
            const s16x8 pf1 = *(const s16x8*)(P2 + i16 * 72 + 32 + quad * 8);
            s16x8 v0, v1;
            v0 = *(const s16x8*)&Vsb[(0 * 16 + i16) * 72 + quad * 8];
            v1 = *(const s16x8*)&Vsb[(0 * 16 + i16) * 72 + 32 + quad * 8];
            O0 = __builtin_amdgcn_mfma_f32_16x16x32_bf16(v0, pf0, O0, 0, 0, 0);
            O0 = __builtin_amdgcn_mfma_f32_16x16x32_bf16(v1, pf1, O0, 0, 0, 0);
            v0 = *(const s16x8*)&Vsb[(1 * 16 + i16) * 72 + quad * 8];
            v1 = *(const s16x8*)&Vsb[(1 * 16 + i16) * 72 + 32 + quad * 8];
            O1 = __builtin_amdgcn_mfma_f32_16x16x32_bf16(v0, pf0, O1, 0, 0, 0);
            O1 = __builtin_amdgcn_mfma_f32_16x16x32_bf16(v1, pf1, O1, 0, 0, 0);
            v0 = *(const s16x8*)&Vsb[(2 * 16 + i16) * 72 + quad * 8];
            v1 = *(const s16x8*)&Vsb[(2 * 16 + i16) * 72 + 32 + quad * 8];
            O2 = __builtin_amdgcn_mfma_f32_16x16x32_bf16(v0, pf0, O2, 0, 0, 0);
            O2 = __builtin_amdgcn_mfma_f32_16x16x32_bf16(v1, pf1, O2, 0, 0, 0);
            v0 = *(const s16x8*)&Vsb[(3 * 16 + i16) * 72 + quad * 8];
            v1 = *(const s16x8*)&Vsb[(3 * 16 + i16) * 72 + 32 + quad * 8];
            O3 = __builtin_amdgcn_mfma_f32_16x16x32_bf16(v0, pf0, O3, 0, 0, 0);
            O3 = __builtin_amdgcn_mfma_f32_16x16x32_bf16(v1, pf1, O3, 0, 0, 0);
        }

        if (has_next) {
            *(s16x8*)&Ks[cur ^ 1][sr * 72 + sseg] = kpre;
            *(s16x8*)&Vs[cur ^ 1][sr * 72 + sseg] = vpre;
            __syncthreads();
        }
    }

    psum += __shfl_xor(psum, 16);
    psum += __shfl_xor(psum, 32);
    const float inv_l = __builtin_amdgcn_rcpf(psum);
    const int b = bh >> 4, hh = bh & 15;
    ushort* Yp = Yb + ((size_t)(b * L + row)) * D + hh * KS + quad * 4;
    f32x4 r;
    r = O0 * inv_l; *(ushort4*)(Yp +  0) = make_ushort4(f2bf(r[0]),f2bf(r[1]),f2bf(r[2]),f2bf(r[3]));
    r = O1 * inv_l; *(ushort4*)(Yp + 16) = make_ushort4(f2bf(r[0]),f2bf(r[1]),f2bf(r[2]),f2bf(r[3]));
    r = O2 * inv_l; *(ushort4*)(Yp + 32) = make_ushort4(f2bf(r[0]),f2bf(r[1]),f2bf(r[2]),f2bf(r[3]));
    r = O3 * inv_l; *(ushort4*)(Yp + 48) = make_ushort4(f2bf(r[0]),f2bf(r[1]),f2bf(r[2]),f2bf(r[3]));
}

// ---------------------------------------------------------------------------
extern "C" void kernel_launch(void* const* d_in, const int* in_sizes, int n_in,
                              void* d_out, int out_size, void* d_ws, size_t ws_size,
                              hipStream_t stream)
{
    const float* x  = (const float*)d_in[0];
    // d_in[1] = mask (unused; causal handled analytically)
    const float* Wq = (const float*)d_in[2];
    const float* Wk = (const float*)d_in[3];
    const float* Wv = (const float*)d_in[4];
    const float* Wo = (const float*)d_in[5];

    const size_t NTOK = (size_t)BBATCH * L;         // 4096
    const size_t SZ   = NTOK * D;                   // 4 M elems
    ushort* xb  = (ushort*)d_ws;                    // [4096][1024]
    ushort* Wt  = xb + SZ;                          // [Wq^T;Wk^T;Wv^T;Wo^T]
    ushort* Qb  = Wt + 4 * (size_t)D * D;           // [bh][l][64]
    ushort* Kb  = Qb + SZ;
    ushort* Vtb = Kb + SZ;                          // [bh][64][l]
    ushort* Yb  = Vtb + SZ;                         // [4096][1024]
    float2* tab = (float2*)Yb;                      // aliases Yb: consumed by
                                                    // qkv before attn writes Yb

    prep<<<dim3(8448), dim3(256), 0, stream>>>(x, Wq, Wk, Wv, Wo, xb, Wt, tab);

    qkv_gemm<<<dim3(32, 24), dim3(256), 0, stream>>>(Wt, xb, tab, Qb, Kb, Vtb);

    attn_mfma<<<dim3(16, 32), dim3(512), 0, stream>>>(Qb, Kb, Vtb, Yb);

    oproj_gemm<<<dim3(16, 32), dim3(256), 0, stream>>>(Yb, Wt + 3 * (size_t)D * D,
                                                       (float*)d_out);
}